// Round 8
// baseline (229.945 us; speedup 1.0000x reference)
//
#include <hip/hip_runtime.h>
#include <hip/hip_bf16.h>
#include <math.h>

#define NROWS 8192
#define DIM   256
#define INV_T 14.285714285714286f   // 1/0.07
#define LOG2E_T 20.60992893360759f  // (1/0.07) * log2(e) -- folded into un
#define EPS_N 1e-8f

typedef __attribute__((ext_vector_type(8))) short short8;
typedef __attribute__((ext_vector_type(4))) float f32x4;

typedef const __attribute__((address_space(1))) void g_void;
typedef __attribute__((address_space(3))) void l_void;

__device__ inline unsigned short f2bf(float x) {
    __hip_bfloat16 h = __float2bfloat16(x);
    return __builtin_bit_cast(unsigned short, h);
}

// ---------------------------------------------------------------------------
// Kernel 1: per-row normalize. un scaled by 1/T*log2(e) (exp2 domain for the
// GEMM); vn plain normalized; diag logit fp32 (natural-log domain); zero rowsum.
// ---------------------------------------------------------------------------
__global__ __launch_bounds__(256) void norm_kernel(
    const float* __restrict__ u, const float* __restrict__ v,
    unsigned short* __restrict__ un, unsigned short* __restrict__ vn,
    float* __restrict__ diag, float* __restrict__ rowsum)
{
    if (threadIdx.x < 4) rowsum[blockIdx.x * 4 + threadIdx.x] = 0.0f;

    const int wid  = threadIdx.x >> 6;
    const int lane = threadIdx.x & 63;
    const int r    = blockIdx.x * 4 + wid;

    const float4* u4 = (const float4*)(u + (size_t)r * DIM);
    const float4* v4 = (const float4*)(v + (size_t)r * DIM);
    float4 a = u4[lane];
    float4 b = v4[lane];

    float ssu = a.x * a.x + a.y * a.y + a.z * a.z + a.w * a.w;
    float ssv = b.x * b.x + b.y * b.y + b.z * b.z + b.w * b.w;
    float duv = a.x * b.x + a.y * b.y + a.z * b.z + a.w * b.w;

    #pragma unroll
    for (int m = 32; m >= 1; m >>= 1) {
        ssu += __shfl_xor(ssu, m);
        ssv += __shfl_xor(ssv, m);
        duv += __shfl_xor(duv, m);
    }

    const float iu  = 1.0f / fmaxf(sqrtf(ssu), EPS_N);
    const float iv  = 1.0f / fmaxf(sqrtf(ssv), EPS_N);
    const float ius = iu * LOG2E_T;          // exp2-domain scale folded into un

    ushort4 pu, pv;
    pu.x = f2bf(a.x * ius); pu.y = f2bf(a.y * ius);
    pu.z = f2bf(a.z * ius); pu.w = f2bf(a.w * ius);
    pv.x = f2bf(b.x * iv);  pv.y = f2bf(b.y * iv);
    pv.z = f2bf(b.z * iv);  pv.w = f2bf(b.w * iv);
    *(ushort4*)(un + (size_t)r * DIM + 4 * lane) = pu;
    *(ushort4*)(vn + (size_t)r * DIM + 4 * lane) = pv;

    if (lane == 0) diag[r] = duv * iu * iv * INV_T;
}

// ---------------------------------------------------------------------------
// Kernel 2: occupancy-first restructure (rounds 3-7 proved the old shape was
// latency-bound at 2 blocks/CU: time invariant 57-64us across four different
// A-handlings; MfmaUtil+VALUBusy ~43%, occupancy 17.6%).
//   Block = 128 i-rows x 512 j-cols, j-steps of 32 cols (16 steps).
//   LDS = 2 x 16KB B-buffers = 32KB -> 4 blocks/CU = 16 waves/CU.
//   Per wave per j-step: 8 ds_read_b128 + 32 MFMA + 16 exp2 (ratios as before,
//   conflict-free k-chunked layout Bs[kg][col][8], measured 0 conflicts).
//   A-frags AGPR-pinned (loaded once). XCD region = i-half x j-quarter
//   (un 2MB + vn 1MB < 4MB L2).
// ---------------------------------------------------------------------------
__global__ __launch_bounds__(256, 4)
void gemm_kernel(
    const unsigned short* __restrict__ un, const unsigned short* __restrict__ vn,
    float* __restrict__ rowsum)
{
    __shared__ unsigned short Bs[2][32][32][8];   // 32 KB

    const int t    = threadIdx.x;
    const int lane = t & 63;
    const int wid  = t >> 6;
    const int wr   = wid >> 1;         // row half within the 128-row panel
    const int wc   = wid & 1;          // col half within the 32-col j-tile
    const int bid  = blockIdx.x;

    // XCD-region mapping: xcd = bid&7 owns (i-half, j-quarter)
    const int xcd = bid & 7;
    const int loc = bid >> 3;          // 0..127
    const int ih  = xcd >> 2;          // 0..1
    const int jq  = xcd & 3;           // 0..3
    const int bx  = loc & 31;          // 0..31
    const int jp  = loc >> 5;          // 0..3
    const int i0  = (ih * 32 + bx) * 128;
    const int j0  = (jq * 4 + jp) * 512;

    const int lr = lane & 15;          // frag row (A) / frag col (B, C/D)
    const int lg = lane >> 4;          // k-group

    // ---- stage one 32-col j-tile (16 KB, 16 instrs, 4 per wave) ----
    // instr (wid,s) fills kg-slabs [bkg, bkg+1]; lane l -> col l&31, dkg l>>5.
    auto stage = [&](int buf, int jt) {
        #pragma unroll
        for (int s = 0; s < 4; ++s) {
            const int bkg = wid * 8 + s * 2;
            const unsigned short* src =
                vn + (size_t)(jt + (lane & 31)) * DIM + (bkg + (lane >> 5)) * 8;
            __builtin_amdgcn_global_load_lds((g_void*)src,
                (l_void*)&Bs[buf][bkg][0][0], 16, 0, 0);
        }
    };

    stage(0, j0);

    // ---- A fragments: rows i0+wr*64+m*16+lr, k = k*32+lg*8 .. +7 ----
    // Pinned in AGPRs (opaque asm def: cannot be remat'd; AGPR class idle).
    short8 av[4][8];
    #pragma unroll
    for (int m = 0; m < 4; ++m) {
        const unsigned short* ar =
            un + (size_t)(i0 + wr * 64 + m * 16 + lr) * DIM + lg * 8;
        #pragma unroll
        for (int k = 0; k < 8; ++k) {
            av[m][k] = *(const short8*)(ar + k * 32);
            asm volatile("" : "+a"(av[m][k]));
        }
    }

    float rs[4][4] = {};

    __syncthreads();   // barrier drain: stage(0) + av loads complete

    int buf = 0;
    #pragma unroll 1
    for (int js = 0; js < 16; ++js) {
        if (js < 15) stage(buf ^ 1, j0 + (js + 1) * 32);

        f32x4 acc[4];
        #pragma unroll
        for (int k = 0; k < 8; ++k) {
            const short8 b = *(const short8*)&Bs[buf][k * 4 + lg][wc * 16 + lr][0];
            if (k == 0) {
                const f32x4 z = {0.f, 0.f, 0.f, 0.f};
                #pragma unroll
                for (int m = 0; m < 4; ++m)
                    acc[m] = __builtin_amdgcn_mfma_f32_16x16x32_bf16(av[m][0], b, z, 0, 0, 0);
            } else {
                #pragma unroll
                for (int m = 0; m < 4; ++m)
                    acc[m] = __builtin_amdgcn_mfma_f32_16x16x32_bf16(av[m][k], b, acc[m], 0, 0, 0);
            }
        }

        // acc is in log2 domain (scale folded into un) -> raw v_exp_f32
        #pragma unroll
        for (int m = 0; m < 4; ++m)
            #pragma unroll
            for (int r = 0; r < 4; ++r)
                rs[m][r] += __builtin_amdgcn_exp2f(acc[m][r]);

        __syncthreads();
        buf ^= 1;
    }

    // ---- per-row reduce across the 16 col-lanes; C/D row = lg*4 + r ----
    #pragma unroll
    for (int m = 0; m < 4; ++m)
        #pragma unroll
        for (int r = 0; r < 4; ++r) {
            float s = rs[m][r];
            s += __shfl_xor(s, 1);
            s += __shfl_xor(s, 2);
            s += __shfl_xor(s, 4);
            s += __shfl_xor(s, 8);
            if (lr == 0)
                atomicAdd(&rowsum[i0 + wr * 64 + m * 16 + lg * 4 + r], s);
        }
}

// ---------------------------------------------------------------------------
// Kernel 3: out = mean(log(rowsum) - diag). 32 blocks, atomic accumulate.
// ---------------------------------------------------------------------------
__global__ __launch_bounds__(256) void finish_kernel(
    const float* __restrict__ rowsum, const float* __restrict__ diag,
    float* __restrict__ out)
{
    __shared__ float red[4];
    const int t    = threadIdx.x;
    const int lane = t & 63;
    const int wid  = t >> 6;
    const int r    = blockIdx.x * 256 + t;

    float c = logf(rowsum[r]) - diag[r];
    #pragma unroll
    for (int m = 32; m >= 1; m >>= 1) c += __shfl_xor(c, m);
    if (lane == 0) red[wid] = c;
    __syncthreads();
    if (t == 0) {
        float s = red[0] + red[1] + red[2] + red[3];
        atomicAdd(out, s * (1.0f / (float)NROWS));
    }
}

// ---------------------------------------------------------------------------
extern "C" void kernel_launch(void* const* d_in, const int* in_sizes, int n_in,
                              void* d_out, int out_size, void* d_ws, size_t ws_size,
                              hipStream_t stream)
{
    const float* u = (const float*)d_in[0];
    const float* v = (const float*)d_in[1];
    float* out = (float*)d_out;

    char* w = (char*)d_ws;
    unsigned short* un = (unsigned short*)w;                                  // 4 MB
    unsigned short* vn = (unsigned short*)(w + (size_t)NROWS * DIM * 2);      // 4 MB
    float* diag   = (float*)(w + (size_t)NROWS * DIM * 4);                    // 32 KB
    float* rowsum = diag + NROWS;                                             // 32 KB

    hipMemsetAsync(out, 0, sizeof(float), stream);
    norm_kernel<<<NROWS / 4, 256, 0, stream>>>(u, v, un, vn, diag, rowsum);
    gemm_kernel<<<1024, 256, 0, stream>>>(un, vn, rowsum);
    finish_kernel<<<NROWS / 256, 256, 0, stream>>>(rowsum, diag, out);
}

// Round 9
// 167.270 us; speedup vs baseline: 1.3747x; 1.3747x over previous
//
#include <hip/hip_runtime.h>
#include <hip/hip_bf16.h>
#include <math.h>

#define NROWS 8192
#define DIM   256
#define INV_T 14.285714285714286f   // 1/0.07
#define LOG2E_T 20.60992893360759f  // (1/0.07) * log2(e) -- folded into un
#define EPS_N 1e-8f
#define GRID_GEMM 512

typedef __attribute__((ext_vector_type(8))) short short8;
typedef __attribute__((ext_vector_type(4))) float f32x4;

typedef const __attribute__((address_space(1))) void g_void;
typedef __attribute__((address_space(3))) void l_void;

__device__ inline unsigned short f2bf(float x) {
    __hip_bfloat16 h = __float2bfloat16(x);
    return __builtin_bit_cast(unsigned short, h);
}

// ---------------------------------------------------------------------------
// Kernel 1: per-row normalize. un scaled by 1/T*log2(e) (exp2 domain for the
// GEMM); vn plain normalized; diag fp32; zero rowsum + done-counter.
// ---------------------------------------------------------------------------
__global__ __launch_bounds__(256) void norm_kernel(
    const float* __restrict__ u, const float* __restrict__ v,
    unsigned short* __restrict__ un, unsigned short* __restrict__ vn,
    float* __restrict__ diag, float* __restrict__ rowsum,
    unsigned int* __restrict__ counter)
{
    if (threadIdx.x < 4) rowsum[blockIdx.x * 4 + threadIdx.x] = 0.0f;
    if (blockIdx.x == 0 && threadIdx.x == 0) *counter = 0u;

    const int wid  = threadIdx.x >> 6;
    const int lane = threadIdx.x & 63;
    const int r    = blockIdx.x * 4 + wid;

    const float4* u4 = (const float4*)(u + (size_t)r * DIM);
    const float4* v4 = (const float4*)(v + (size_t)r * DIM);
    float4 a = u4[lane];
    float4 b = v4[lane];

    float ssu = a.x * a.x + a.y * a.y + a.z * a.z + a.w * a.w;
    float ssv = b.x * b.x + b.y * b.y + b.z * b.z + b.w * b.w;
    float duv = a.x * b.x + a.y * b.y + a.z * b.z + a.w * b.w;

    #pragma unroll
    for (int m = 32; m >= 1; m >>= 1) {
        ssu += __shfl_xor(ssu, m);
        ssv += __shfl_xor(ssv, m);
        duv += __shfl_xor(duv, m);
    }

    const float iu  = 1.0f / fmaxf(sqrtf(ssu), EPS_N);
    const float iv  = 1.0f / fmaxf(sqrtf(ssv), EPS_N);
    const float ius = iu * LOG2E_T;

    ushort4 pu, pv;
    pu.x = f2bf(a.x * ius); pu.y = f2bf(a.y * ius);
    pu.z = f2bf(a.z * ius); pu.w = f2bf(a.w * ius);
    pv.x = f2bf(b.x * iv);  pv.y = f2bf(b.y * iv);
    pv.z = f2bf(b.z * iv);  pv.w = f2bf(b.w * iv);
    *(ushort4*)(un + (size_t)r * DIM + 4 * lane) = pu;
    *(ushort4*)(vn + (size_t)r * DIM + 4 * lane) = pv;

    if (lane == 0) diag[r] = duv * iu * iv * INV_T;
}

// ---------------------------------------------------------------------------
// Kernel 2: BARRIER-FREE per-wave flash GEMM.
// Rounds 4-8 evidence: A-residency forces 2 waves/EU; with a __syncthreads
// every j-step the pipes serialize (measured cy/j-step == serial sum of
// MFMA+LDS+VALU+stage). Fix: waves share NOTHING.
//   wave = 64 i-rows x 512 j-cols; j-steps of 16 cols (32 steps).
//   A (64x256) pinned in AGPRs (round-7 pattern, FETCH-verified no spill).
//   B: per-wave private 2x8KB LDS slabs, global_load_lds, counted vmcnt(8)
//   waits (prev slab's loads get a full ~1200cy compute phase to land).
//   Stage writes buf^1 while compute reads buf -> no alias; a zero-cost
//   compiler barrier at loop end stops cross-iteration hoisting into the
//   buffer the PREVIOUS iteration was reading.
//   Per wave j-step: 8 ds_read_b128 + 32 MFMA (4:1) + 16 exp2. No syncs.
// Finale fused via done-counter: last block computes mean(log(rowsum)-diag).
// ---------------------------------------------------------------------------
__global__ __launch_bounds__(256, 2)
void gemm_kernel(
    const unsigned short* __restrict__ un, const unsigned short* __restrict__ vn,
    float* __restrict__ rowsum, const float* __restrict__ diag,
    unsigned int* __restrict__ counter, float* __restrict__ out)
{
    __shared__ unsigned short Bs[4][2][4096];   // [wave][buf][8KB]: 64 KB

    const int t    = threadIdx.x;
    const int lane = t & 63;
    const int wid  = t >> 6;
    const int bid  = blockIdx.x;

    const int rowpanel = bid >> 4;      // 0..31
    const int jsl      = bid & 15;      // 0..15
    const int i0 = rowpanel * 256 + wid * 64;
    const int j0 = jsl * 512;

    const int lr = lane & 15;           // frag row (A) / frag col (B, C/D)
    const int lg = lane >> 4;           // k-group

    // ---- per-wave stage: 16 cols x 256 k -> [kg 32][col 16][8] (8 instrs)
    // lane l sources col l&15, k-chunk l>>4; dst linear (rule 21: pre-swizzled
    // global source, linear LDS dest). slab s covers kg = s*4 + lg.
    const unsigned short* src0 = vn + (size_t)(j0 + lr) * DIM + lg * 8;
    auto stage = [&](int buf, int js) {
        const unsigned short* src = src0 + (size_t)js * 16 * DIM;
        unsigned short* dst = &Bs[wid][buf][0];
        #pragma unroll
        for (int s = 0; s < 8; ++s) {
            __builtin_amdgcn_global_load_lds((g_void*)(src + s * 32),
                (l_void*)(dst + s * 512), 16, 0, 0);
        }
    };

    stage(0, 0);

    // ---- A fragments (AGPR-pinned; round-7 pattern) ----
    short8 av[4][8];
    #pragma unroll
    for (int m = 0; m < 4; ++m) {
        const unsigned short* ar =
            un + (size_t)(i0 + m * 16 + lr) * DIM + lg * 8;
        #pragma unroll
        for (int k = 0; k < 8; ++k) {
            av[m][k] = *(const short8*)(ar + k * 32);
            asm volatile("" : "+a"(av[m][k]));
        }
    }

    float rs[4][4] = {};

    #pragma unroll 1
    for (int js = 0; js < 32; ++js) {
        const int buf = js & 1;
        if (js < 31) {
            stage(buf ^ 1, js + 1);
            asm volatile("s_waitcnt vmcnt(8)" ::: "memory");  // drain slab js
        } else {
            asm volatile("s_waitcnt vmcnt(0)" ::: "memory");
        }

        const unsigned short* bp = &Bs[wid][buf][0];
        f32x4 acc[4];
        #pragma unroll
        for (int kk = 0; kk < 8; ++kk) {
            const short8 b = *(const short8*)(bp + kk * 512 + lane * 8);
            if (kk == 0) {
                const f32x4 z = {0.f, 0.f, 0.f, 0.f};
                #pragma unroll
                for (int m = 0; m < 4; ++m)
                    acc[m] = __builtin_amdgcn_mfma_f32_16x16x32_bf16(av[m][0], b, z, 0, 0, 0);
            } else {
                #pragma unroll
                for (int m = 0; m < 4; ++m)
                    acc[m] = __builtin_amdgcn_mfma_f32_16x16x32_bf16(av[m][kk], b, acc[m], 0, 0, 0);
            }
        }

        #pragma unroll
        for (int m = 0; m < 4; ++m)
            #pragma unroll
            for (int r = 0; r < 4; ++r)
                rs[m][r] += __builtin_amdgcn_exp2f(acc[m][r]);

        // zero-cost fence: next iter's stage cannot hoist above this point
        asm volatile("" ::: "memory");
    }

    // ---- per-row reduce across the 16 col-lanes; C/D row = lg*4 + r ----
    #pragma unroll
    for (int m = 0; m < 4; ++m)
        #pragma unroll
        for (int r = 0; r < 4; ++r) {
            float s = rs[m][r];
            s += __shfl_xor(s, 1);
            s += __shfl_xor(s, 2);
            s += __shfl_xor(s, 4);
            s += __shfl_xor(s, 8);
            if (lr == 0)
                atomicAdd(&rowsum[i0 + m * 16 + lg * 4 + r], s);
        }

    // ---- fused finale: last finished block computes the mean ----
    __threadfence();
    __syncthreads();
    __shared__ unsigned int lastflag;
    if (t == 0) {
        unsigned int old = atomicAdd(counter, 1u);
        lastflag = (old == GRID_GEMM - 1) ? 1u : 0u;
    }
    __syncthreads();
    if (lastflag) {
        __threadfence();
        __shared__ float red[4];
        float c = 0.0f;
        #pragma unroll
        for (int q = 0; q < NROWS / 256; ++q) {
            const int r = t + 256 * q;
            const float sv = __hip_atomic_load(&rowsum[r], __ATOMIC_RELAXED,
                                               __HIP_MEMORY_SCOPE_AGENT);
            c += logf(sv) - diag[r];
        }
        #pragma unroll
        for (int m = 32; m >= 1; m >>= 1) c += __shfl_xor(c, m);
        if (lane == 0) red[wid] = c;
        __syncthreads();
        if (t == 0)
            out[0] = (red[0] + red[1] + red[2] + red[3]) * (1.0f / (float)NROWS);
    }
}

// ---------------------------------------------------------------------------
extern "C" void kernel_launch(void* const* d_in, const int* in_sizes, int n_in,
                              void* d_out, int out_size, void* d_ws, size_t ws_size,
                              hipStream_t stream)
{
    const float* u = (const float*)d_in[0];
    const float* v = (const float*)d_in[1];
    float* out = (float*)d_out;

    char* w = (char*)d_ws;
    unsigned short* un = (unsigned short*)w;                                  // 4 MB
    unsigned short* vn = (unsigned short*)(w + (size_t)NROWS * DIM * 2);      // 4 MB
    float* diag   = (float*)(w + (size_t)NROWS * DIM * 4);                    // 32 KB
    float* rowsum = diag + NROWS;                                             // 32 KB
    unsigned int* counter = (unsigned int*)(rowsum + NROWS);

    norm_kernel<<<NROWS / 4, 256, 0, stream>>>(u, v, un, vn, diag, rowsum, counter);
    gemm_kernel<<<GRID_GEMM, 256, 0, stream>>>(un, vn, rowsum, diag, counter, out);
}